// Round 15
// baseline (135.131 us; speedup 1.0000x reference)
//
#include <hip/hip_runtime.h>
#include <math.h>

#define BATCH  2048
#define FEAT   2048
#define LUTSZ  64
#define TF     128           // features per tile (sl = 32 KB)
#define NCH    2             // chunks per tile = TF/64
#define SLOTS  4             // row slots per iteration
#define GROUPS 64
#define RPB    32            // rows per block
#define ITERS  (RPB / SLOTS) // 8

typedef float f32x2 __attribute__((ext_vector_type(2)));
typedef int   i32x2 __attribute__((ext_vector_type(2)));
typedef float f32x4 __attribute__((ext_vector_type(4)));

// ---------------------------------------------------------------------------
// Round-15 = round-14 (best, 125us) with two decoupling changes:
//  * TF=128: sl 32KB + xsh[4 slots] 32KB = 64KB -> still 2 blocks/CU, but
//    4 rows per barrier-pair (16 barriers/kernel vs 32) -- halves the
//    all-waves coupling to the slowest gatherer.
//  * depth-2 r prefetch (i+1 and i+2 in flight) -> 2x r bytes in flight
//    (Little's law: observed ~2TB/s vs fill-kernel's 7TB/s calibration).
// Machinery unchanged & proven: ballot transpose (r9), raw lgkmcnt+s_barrier
// (r14), slut precompute w/ ws check + in-kernel exp fallback (r14),
// exact f32 chain: (v+1.0f)*0.5f; 1.0f/(1.0f+RN32(exp_f64(-v))).
// ---------------------------------------------------------------------------

__device__ __forceinline__ void barrier_keep_vm() {
    __builtin_amdgcn_sched_barrier(0);
    asm volatile("s_waitcnt lgkmcnt(0)\n\ts_barrier" ::: "memory");
    __builtin_amdgcn_sched_barrier(0);
}

__global__ __launch_bounds__(256) void sigmoid_lut_kernel(
    const float* __restrict__ lut1, const float* __restrict__ lut2,
    float* __restrict__ slut1, float* __restrict__ slut2)
{
    const int n = FEAT * LUTSZ;
    int i = blockIdx.x * 256 + threadIdx.x;
    if (i < n) {
        float v = lut1[i];
        float e = (float)exp(-(double)v);
        slut1[i] = 1.0f / (1.0f + e);
    } else {
        i -= n;
        float v = lut2[i];
        float e = (float)exp(-(double)v);
        slut2[i] = 1.0f / (1.0f + e);
    }
}

// L: 0 = transform-in (+sigmoid-lut), 1 = sigmoid-lut, 2 = raw lut
// PRE: lutg already sigmoid'd
template<int L, bool PRE>
__global__ __launch_bounds__(512, 4) void lut_tile3(
    const float* __restrict__ xin, const float* __restrict__ rr,
    const int* __restrict__ connect, const float* __restrict__ lutg,
    float* __restrict__ yout)
{
    __shared__ float sl[TF * LUTSZ];     // 32 KiB
    __shared__ float xsh[SLOTS][FEAT];   // 32 KiB (4 row slots)

    const int tile = blockIdx.x, grp = blockIdx.y;
    const int f0   = tile * TF;
    const int tid  = threadIdx.x, lane = tid & 63, w = tid >> 6;
    const int slot = w >> 1;             // 0..3: row slot this wave computes
    const int ch   = w & 1;              // chunk
    const int fc   = f0 + ch * 64;

    // ---- stage lut tile ----
    for (int i = tid; i < TF * LUTSZ; i += 512) {
        float v = lutg[(size_t)f0 * LUTSZ + i];
        if (!PRE && L < 2) {
            float e = (float)exp(-(double)v);   // correctly-rounded f32 exp
            v = 1.0f / (1.0f + e);              // f32 IEEE chain
        }
        sl[i] = v;
    }

    // ---- connect regs for this wave's chunk (scrambled ballot layout) ----
    i32x2 cc0, cc1, cc2;
    {
        const i32x2* cg = reinterpret_cast<const i32x2*>(
            connect + (size_t)fc * 6);
        cc0 = cg[lane]; cc1 = cg[64 + lane]; cc2 = cg[128 + lane];
    }

    const int b0 = grp * RPB;

    // x staging map: thread t covers 4 f32x4 of row (b0 + SLOTS*i + srow):
    //   srow = t>>7, positions (t&127)*4 + 512*k, k=0..3
    const int srow = tid >> 7;
    const int scol = (tid & 127) * 4;

    // ---- prologue: x rows 0..3, r(iter0), r(iter1) ----
    f32x4 nx0, nx1, nx2, nx3;
    {
        const float* xp = xin + (size_t)(b0 + srow) * FEAT + scol;
        nx0 = *reinterpret_cast<const f32x4*>(xp);
        nx1 = *reinterpret_cast<const f32x4*>(xp + 512);
        nx2 = *reinterpret_cast<const f32x4*>(xp + 1024);
        nx3 = *reinterpret_cast<const f32x4*>(xp + 1536);
    }
    f32x2 r0, r1, r2, p0, p1, p2;
    {
        const f32x2* rg = reinterpret_cast<const f32x2*>(
            rr + ((size_t)(b0 + slot) * FEAT + fc) * 6);
        r0 = rg[lane]; r1 = rg[64 + lane]; r2 = rg[128 + lane];
    }
    {
        const f32x2* rg = reinterpret_cast<const f32x2*>(
            rr + ((size_t)(b0 + SLOTS + slot) * FEAT + fc) * 6);
        p0 = rg[lane]; p1 = rg[64 + lane]; p2 = rg[128 + lane];
    }
    {
        f32x4 a0 = nx0, a1 = nx1, a2 = nx2, a3 = nx3;
        if (L == 0) {
            a0 = (a0 + 1.0f) * 0.5f; a1 = (a1 + 1.0f) * 0.5f;
            a2 = (a2 + 1.0f) * 0.5f; a3 = (a3 + 1.0f) * 0.5f;
        }
        *reinterpret_cast<f32x4*>(&xsh[srow][scol])        = a0;
        *reinterpret_cast<f32x4*>(&xsh[srow][scol + 512])  = a1;
        *reinterpret_cast<f32x4*>(&xsh[srow][scol + 1024]) = a2;
        *reinterpret_cast<f32x4*>(&xsh[srow][scol + 1536]) = a3;
    }
    barrier_keep_vm();   // sl + xsh visible

    for (int i = 0; i < ITERS; ++i) {
        const int b = b0 + SLOTS * i + slot;

        // ---- depth-2 r prefetch (iter i+2) ----
        f32x2 q0, q1, q2;
        if (i + 2 < ITERS) {
            const f32x2* rg = reinterpret_cast<const f32x2*>(
                rr + ((size_t)(b + 2 * SLOTS) * FEAT + fc) * 6);
            q0 = rg[lane]; q1 = rg[64 + lane]; q2 = rg[128 + lane];
        }
        // ---- x prefetch (iter i+1) ----
        if (i + 1 < ITERS) {
            const float* xp = xin +
                (size_t)(b0 + SLOTS * (i + 1) + srow) * FEAT + scol;
            nx0 = *reinterpret_cast<const f32x4*>(xp);
            nx1 = *reinterpret_cast<const f32x4*>(xp + 512);
            nx2 = *reinterpret_cast<const f32x4*>(xp + 1024);
            nx3 = *reinterpret_cast<const f32x4*>(xp + 1536);
        }

        // ---- ballot transpose (r9-verified) + LDS lut gather ----
        const float* xw = xsh[slot];
        const unsigned long long B0 = __ballot(xw[cc0[0]] >= r0[0]);
        const unsigned long long B1 = __ballot(xw[cc0[1]] >= r0[1]);
        const unsigned long long B2 = __ballot(xw[cc1[0]] >= r1[0]);
        const unsigned long long B3 = __ballot(xw[cc1[1]] >= r1[1]);
        const unsigned long long B4 = __ballot(xw[cc2[0]] >= r2[0]);
        const unsigned long long B5 = __ballot(xw[cc2[1]] >= r2[1]);

        int idx = 0;
        #pragma unroll
        for (int j = 0; j < 6; ++j) {
            const int e = 6 * lane + j;          // even => e&1 == j&1
            const int g = e >> 7;
            const unsigned long long src =
                (j & 1) ? ((g == 0) ? B1 : (g == 1) ? B3 : B5)
                        : ((g == 0) ? B0 : (g == 1) ? B2 : B4);
            idx |= (int)((src >> ((e & 127) >> 1)) & 1ull) << j;
        }

        const float v = sl[(ch * 64 + lane) * LUTSZ + idx];
        yout[(size_t)b * FEAT + fc + lane] = v;

        // ---- rotate r registers ----
        r0 = p0; r1 = p1; r2 = p2;
        p0 = q0; p1 = q1; p2 = q2;

        // ---- rotate the shared x buffer ----
        barrier_keep_vm();                // all waves done gathering iter i
        if (i + 1 < ITERS) {
            f32x4 a0 = nx0, a1 = nx1, a2 = nx2, a3 = nx3;
            if (L == 0) {
                a0 = (a0 + 1.0f) * 0.5f; a1 = (a1 + 1.0f) * 0.5f;
                a2 = (a2 + 1.0f) * 0.5f; a3 = (a3 + 1.0f) * 0.5f;
            }
            *reinterpret_cast<f32x4*>(&xsh[srow][scol])        = a0;
            *reinterpret_cast<f32x4*>(&xsh[srow][scol + 512])  = a1;
            *reinterpret_cast<f32x4*>(&xsh[srow][scol + 1024]) = a2;
            *reinterpret_cast<f32x4*>(&xsh[srow][scol + 1536]) = a3;
            barrier_keep_vm();            // new rows visible
        }
    }
}

extern "C" void kernel_launch(void* const* d_in, const int* in_sizes, int n_in,
                              void* d_out, int out_size, void* d_ws, size_t ws_size,
                              hipStream_t stream) {
    const float* inputs = (const float*)d_in[0];
    const float* r1     = (const float*)d_in[1];
    const float* r2     = (const float*)d_in[2];
    const float* r3     = (const float*)d_in[3];
    const float* lut1   = (const float*)d_in[4];
    const float* lut2   = (const float*)d_in[5];
    const float* lut3   = (const float*)d_in[6];
    const int*   c1     = (const int*)d_in[7];
    const int*   c2     = (const int*)d_in[8];
    const int*   c3     = (const int*)d_in[9];
    float* out = (float*)d_out;

    const size_t n    = (size_t)BATCH * FEAT;
    const size_t lutn = (size_t)FEAT * LUTSZ;
    dim3 grid(FEAT / TF, GROUPS), block(512);

    if (ws_size >= (2 * lutn + 2 * n) * sizeof(float)) {
        float* slut1 = (float*)d_ws;
        float* slut2 = slut1 + lutn;
        float* ws1   = slut2 + lutn;
        float* ws2   = ws1 + n;
        sigmoid_lut_kernel<<<dim3(2 * lutn / 256), dim3(256), 0, stream>>>(
            lut1, lut2, slut1, slut2);
        lut_tile3<0, true ><<<grid, block, 0, stream>>>(inputs, r1, c1, slut1, ws1);
        lut_tile3<1, true ><<<grid, block, 0, stream>>>(ws1,    r2, c2, slut2, ws2);
        lut_tile3<2, true ><<<grid, block, 0, stream>>>(ws2,    r3, c3, lut3,  out);
    } else {
        float* ws1 = (float*)d_ws;
        float* ws2 = ws1 + n;
        lut_tile3<0, false><<<grid, block, 0, stream>>>(inputs, r1, c1, lut1, ws1);
        lut_tile3<1, false><<<grid, block, 0, stream>>>(ws1,    r2, c2, lut2, ws2);
        lut_tile3<2, false><<<grid, block, 0, stream>>>(ws2,    r3, c3, lut3, out);
    }
}

// Round 16
// 103.542 us; speedup vs baseline: 1.3051x; 1.3051x over previous
//
#include <hip/hip_runtime.h>
#include <math.h>

#define BATCH  2048
#define FEAT   2048
#define LUTSZ  64
#define TF     256
#define GROUPS 64
#define RPB    32            // rows per block
#define ITERS  (RPB / 2)     // 2 rows per iteration

typedef float f32x2 __attribute__((ext_vector_type(2)));
typedef int   i32x2 __attribute__((ext_vector_type(2)));
typedef float f32x4 __attribute__((ext_vector_type(4)));

// ---------------------------------------------------------------------------
// Round-16 = round-14 VERBATIM (best: 125us; TF-series proved 256>128>64)
// + XCD-group-pinning block swizzle (T1).
//
// r14 grid (tile,group) x-fastest put the 8 tile-blocks of a group (which
// share the same 32 x-rows, 8x re-read each) on 8 DIFFERENT XCDs -> every
// x re-read was a cross-XCD/L3 access. Launching a flat 512-block grid and
// decoding fid = tile*64 + group gives all 8 tile-blocks of group g
// fid = g (mod 8) -> SAME XCD -> x re-reads become local-L2 hits; each XCD
// caches the full 512KB slut as well. Pure bijective index permutation.
//
// Machinery proven: ballot transpose (r9), raw lgkmcnt+s_barrier keeping
// vmem in flight (r14), slut precompute w/ ws check + in-kernel exp
// fallback (r14), exact f32 chain: (v+1.0f)*0.5f;
// sigmoid = 1.0f/(1.0f + RN32(exp_f64(-v))); f32 compares.
// ---------------------------------------------------------------------------

__device__ __forceinline__ void barrier_keep_vm() {
    __builtin_amdgcn_sched_barrier(0);
    asm volatile("s_waitcnt lgkmcnt(0)\n\ts_barrier" ::: "memory");
    __builtin_amdgcn_sched_barrier(0);
}

__global__ __launch_bounds__(256) void sigmoid_lut_kernel(
    const float* __restrict__ lut1, const float* __restrict__ lut2,
    float* __restrict__ slut1, float* __restrict__ slut2)
{
    const int n = FEAT * LUTSZ;
    int i = blockIdx.x * 256 + threadIdx.x;
    if (i < n) {
        float v = lut1[i];
        float e = (float)exp(-(double)v);
        slut1[i] = 1.0f / (1.0f + e);
    } else {
        i -= n;
        float v = lut2[i];
        float e = (float)exp(-(double)v);
        slut2[i] = 1.0f / (1.0f + e);
    }
}

// L: 0 = transform-in (+sigmoid-lut), 1 = sigmoid-lut, 2 = raw lut
// PRE: lutg already sigmoid'd -> no exp in staging
template<int L, bool PRE>
__global__ __launch_bounds__(512, 4) void lut_tile2(
    const float* __restrict__ xin, const float* __restrict__ rr,
    const int* __restrict__ connect, const float* __restrict__ lutg,
    float* __restrict__ yout)
{
    __shared__ float sl[TF * LUTSZ];   // 64 KiB
    __shared__ float xsh[2][FEAT];     // 16 KiB  (2 row slots)

    // XCD swizzle: fid = tile*GROUPS + grp  ->  all 8 tile-blocks of a group
    // share fid mod 8 -> same XCD -> shared x rows are local-L2 hits.
    const int fid  = blockIdx.x;
    const int tile = fid >> 6;          // 0..7
    const int grp  = fid & 63;          // 0..63
    const int f0   = tile * TF;
    const int tid  = threadIdx.x, lane = tid & 63, w = tid >> 6;
    const int slot = w >> 2;           // 0/1: which row this wave computes
    const int ch   = w & 3;            // which 64-feature chunk
    const int fc   = f0 + ch * 64;

    // ---- stage lut tile ----
    for (int i = tid; i < TF * LUTSZ; i += 512) {
        float v = lutg[(size_t)f0 * LUTSZ + i];
        if (!PRE && L < 2) {
            float e = (float)exp(-(double)v);   // correctly-rounded f32 exp
            v = 1.0f / (1.0f + e);              // f32 IEEE chain
        }
        sl[i] = v;
    }

    // ---- connect regs for this wave's chunk (scrambled ballot layout) ----
    i32x2 cc0, cc1, cc2;
    {
        const i32x2* cg = reinterpret_cast<const i32x2*>(
            connect + (size_t)fc * 6);
        cc0 = cg[lane]; cc1 = cg[64 + lane]; cc2 = cg[128 + lane];
    }

    const int b0 = grp * RPB;

    // x staging map: thread covers 4 floats at xcol and 4 at xcol+1024 of
    // row (b0 + 2i + xrow_off)  -> conflict-free b128 LDS writes.
    const int xrow_off = tid >> 8;          // 0/1
    const int xcol     = (tid & 255) * 4;   // float offset

    // ---- iter-0 prefetch: x rows 0,1 then r(row slot, iter 0) ----
    f32x4 nxa, nxb;
    {
        const float* xp = xin + (size_t)(b0 + xrow_off) * FEAT;
        nxa = *reinterpret_cast<const f32x4*>(xp + xcol);
        nxb = *reinterpret_cast<const f32x4*>(xp + xcol + 1024);
    }
    f32x2 r0, r1, r2;
    {
        const f32x2* rg = reinterpret_cast<const f32x2*>(
            rr + ((size_t)(b0 + slot) * FEAT + fc) * 6);
        r0 = rg[lane]; r1 = rg[64 + lane]; r2 = rg[128 + lane];
    }
    {
        f32x4 a = nxa, b = nxb;
        if (L == 0) { a = (a + 1.0f) * 0.5f; b = (b + 1.0f) * 0.5f; }
        *reinterpret_cast<f32x4*>(&xsh[xrow_off][xcol])        = a;
        *reinterpret_cast<f32x4*>(&xsh[xrow_off][xcol + 1024]) = b;
    }
    barrier_keep_vm();   // sl + xsh visible to all waves

    for (int i = 0; i < ITERS; ++i) {
        const int b = b0 + 2 * i + slot;

        // ---- prefetch iter i+1: x first, then r (so the x vmcnt-wait at the
        //      LDS write leaves the r loads in flight) ----
        if (i + 1 < ITERS) {
            const float* xp = xin + (size_t)(b0 + 2 * (i + 1) + xrow_off) * FEAT;
            nxa = *reinterpret_cast<const f32x4*>(xp + xcol);
            nxb = *reinterpret_cast<const f32x4*>(xp + xcol + 1024);
        }
        f32x2 n0, n1, n2;
        if (i + 1 < ITERS) {
            const f32x2* rg = reinterpret_cast<const f32x2*>(
                rr + ((size_t)(b + 2) * FEAT + fc) * 6);
            n0 = rg[lane]; n1 = rg[64 + lane]; n2 = rg[128 + lane];
        }

        // ---- ballot transpose (r9-verified) + LDS lut gather ----
        const float* xw = xsh[slot];
        const unsigned long long B0 = __ballot(xw[cc0[0]] >= r0[0]);
        const unsigned long long B1 = __ballot(xw[cc0[1]] >= r0[1]);
        const unsigned long long B2 = __ballot(xw[cc1[0]] >= r1[0]);
        const unsigned long long B3 = __ballot(xw[cc1[1]] >= r1[1]);
        const unsigned long long B4 = __ballot(xw[cc2[0]] >= r2[0]);
        const unsigned long long B5 = __ballot(xw[cc2[1]] >= r2[1]);

        int idx = 0;
        #pragma unroll
        for (int j = 0; j < 6; ++j) {
            const int e = 6 * lane + j;          // even => e&1 == j&1
            const int g = e >> 7;
            const unsigned long long src =
                (j & 1) ? ((g == 0) ? B1 : (g == 1) ? B3 : B5)
                        : ((g == 0) ? B0 : (g == 1) ? B2 : B4);
            idx |= (int)((src >> ((e & 127) >> 1)) & 1ull) << j;
        }

        const float v = sl[(ch * 64 + lane) * LUTSZ + idx];
        yout[(size_t)b * FEAT + fc + lane] = v;

        r0 = n0; r1 = n1; r2 = n2;

        // ---- rotate the shared x buffer ----
        barrier_keep_vm();                // all waves done gathering iter i
        if (i + 1 < ITERS) {
            f32x4 a = nxa, bb = nxb;      // vmcnt-waits x only (r after x)
            if (L == 0) { a = (a + 1.0f) * 0.5f; bb = (bb + 1.0f) * 0.5f; }
            *reinterpret_cast<f32x4*>(&xsh[xrow_off][xcol])        = a;
            *reinterpret_cast<f32x4*>(&xsh[xrow_off][xcol + 1024]) = bb;
            barrier_keep_vm();            // new rows visible
        }
    }
}

extern "C" void kernel_launch(void* const* d_in, const int* in_sizes, int n_in,
                              void* d_out, int out_size, void* d_ws, size_t ws_size,
                              hipStream_t stream) {
    const float* inputs = (const float*)d_in[0];
    const float* r1     = (const float*)d_in[1];
    const float* r2     = (const float*)d_in[2];
    const float* r3     = (const float*)d_in[3];
    const float* lut1   = (const float*)d_in[4];
    const float* lut2   = (const float*)d_in[5];
    const float* lut3   = (const float*)d_in[6];
    const int*   c1     = (const int*)d_in[7];
    const int*   c2     = (const int*)d_in[8];
    const int*   c3     = (const int*)d_in[9];
    float* out = (float*)d_out;

    const size_t n    = (size_t)BATCH * FEAT;
    const size_t lutn = (size_t)FEAT * LUTSZ;
    dim3 grid((FEAT / TF) * GROUPS), block(512);   // flat 512 blocks, swizzled

    if (ws_size >= (2 * lutn + 2 * n) * sizeof(float)) {
        float* slut1 = (float*)d_ws;
        float* slut2 = slut1 + lutn;
        float* ws1   = slut2 + lutn;
        float* ws2   = ws1 + n;
        sigmoid_lut_kernel<<<dim3(2 * lutn / 256), dim3(256), 0, stream>>>(
            lut1, lut2, slut1, slut2);
        lut_tile2<0, true ><<<grid, block, 0, stream>>>(inputs, r1, c1, slut1, ws1);
        lut_tile2<1, true ><<<grid, block, 0, stream>>>(ws1,    r2, c2, slut2, ws2);
        lut_tile2<2, true ><<<grid, block, 0, stream>>>(ws2,    r3, c3, lut3,  out);
    } else {
        float* ws1 = (float*)d_ws;
        float* ws2 = ws1 + n;
        lut_tile2<0, false><<<grid, block, 0, stream>>>(inputs, r1, c1, lut1, ws1);
        lut_tile2<1, false><<<grid, block, 0, stream>>>(ws1,    r2, c2, lut2, ws2);
        lut_tile2<2, false><<<grid, block, 0, stream>>>(ws2,    r3, c3, lut3, out);
    }
}

// Round 17
// 101.931 us; speedup vs baseline: 1.3257x; 1.0158x over previous
//
#include <hip/hip_runtime.h>
#include <math.h>

#define BATCH  2048
#define FEAT   2048
#define LUTSZ  64
#define TF     256
#define GROUPS 64
#define RPB    32            // rows per block
#define ITERS  (RPB / 2)     // 2 rows per iteration

typedef float f32x2 __attribute__((ext_vector_type(2)));
typedef int   i32x2 __attribute__((ext_vector_type(2)));
typedef float f32x4 __attribute__((ext_vector_type(4)));

// ---------------------------------------------------------------------------
// Round-17 = round-16 (103.5us: TF=256 tile + XCD-group-pin swizzle) with the
// PRE path made UNCONDITIONAL:
//   d_out doubles as the layer-1 intermediate (same [B,F] f32 shape, fully
//   rewritten by layer 3, no cross-layer aliasing):
//     L1: inputs -> d_out ; L2: d_out -> ws2 ; L3: ws2 -> d_out
//   ws = slut1 + slut2 + ws2 = 17.8MB  (< the 33.55MB empirically proven),
//   so slut is ALWAYS precomputed -- the in-kernel f64-exp fallback (16K
//   exps per block x 512 blocks x 2 layers if ws_size < 34.6MB) is deleted.
//
// Machinery proven: ballot transpose (r9), raw lgkmcnt+s_barrier keeping
// vmem in flight (r14), XCD swizzle fid=tile*64+grp (r16, -17%),
// exact f32 chain: (v+1.0f)*0.5f; sigmoid 1.0f/(1.0f+RN32(exp_f64(-v))).
// ---------------------------------------------------------------------------

__device__ __forceinline__ void barrier_keep_vm() {
    __builtin_amdgcn_sched_barrier(0);
    asm volatile("s_waitcnt lgkmcnt(0)\n\ts_barrier" ::: "memory");
    __builtin_amdgcn_sched_barrier(0);
}

__global__ __launch_bounds__(256) void sigmoid_lut_kernel(
    const float* __restrict__ lut1, const float* __restrict__ lut2,
    float* __restrict__ slut1, float* __restrict__ slut2)
{
    const int n = FEAT * LUTSZ;
    int i = blockIdx.x * 256 + threadIdx.x;
    if (i < n) {
        float v = lut1[i];
        float e = (float)exp(-(double)v);     // correctly-rounded f32 exp
        slut1[i] = 1.0f / (1.0f + e);         // f32 IEEE chain (matches np)
    } else {
        i -= n;
        float v = lut2[i];
        float e = (float)exp(-(double)v);
        slut2[i] = 1.0f / (1.0f + e);
    }
}

// L: 0 = transform-in, 1 = plain input (lutg is slut or raw lut3)
template<int L>
__global__ __launch_bounds__(512, 4) void lut_tile2(
    const float* __restrict__ xin, const float* __restrict__ rr,
    const int* __restrict__ connect, const float* __restrict__ lutg,
    float* __restrict__ yout)
{
    __shared__ float sl[TF * LUTSZ];   // 64 KiB
    __shared__ float xsh[2][FEAT];     // 16 KiB  (2 row slots)

    // XCD swizzle: fid = tile*GROUPS + grp -> the 8 tile-blocks of a group
    // share fid mod 8 -> same XCD -> shared x rows are local-L2 hits.
    const int fid  = blockIdx.x;
    const int tile = fid >> 6;          // 0..7
    const int grp  = fid & 63;          // 0..63
    const int f0   = tile * TF;
    const int tid  = threadIdx.x, lane = tid & 63, w = tid >> 6;
    const int slot = w >> 2;           // 0/1: which row this wave computes
    const int ch   = w & 3;            // which 64-feature chunk
    const int fc   = f0 + ch * 64;

    // ---- stage lut tile (already sigmoid'd for layers 1-2) ----
    for (int i = tid; i < TF * LUTSZ; i += 512)
        sl[i] = lutg[(size_t)f0 * LUTSZ + i];

    // ---- connect regs for this wave's chunk (scrambled ballot layout) ----
    i32x2 cc0, cc1, cc2;
    {
        const i32x2* cg = reinterpret_cast<const i32x2*>(
            connect + (size_t)fc * 6);
        cc0 = cg[lane]; cc1 = cg[64 + lane]; cc2 = cg[128 + lane];
    }

    const int b0 = grp * RPB;

    // x staging map: thread covers 4 floats at xcol and 4 at xcol+1024 of
    // row (b0 + 2i + xrow_off)  -> conflict-free b128 LDS writes.
    const int xrow_off = tid >> 8;          // 0/1
    const int xcol     = (tid & 255) * 4;   // float offset

    // ---- iter-0 prefetch: x rows 0,1 then r(row slot, iter 0) ----
    f32x4 nxa, nxb;
    {
        const float* xp = xin + (size_t)(b0 + xrow_off) * FEAT;
        nxa = *reinterpret_cast<const f32x4*>(xp + xcol);
        nxb = *reinterpret_cast<const f32x4*>(xp + xcol + 1024);
    }
    f32x2 r0, r1, r2;
    {
        const f32x2* rg = reinterpret_cast<const f32x2*>(
            rr + ((size_t)(b0 + slot) * FEAT + fc) * 6);
        r0 = rg[lane]; r1 = rg[64 + lane]; r2 = rg[128 + lane];
    }
    {
        f32x4 a = nxa, b = nxb;
        if (L == 0) { a = (a + 1.0f) * 0.5f; b = (b + 1.0f) * 0.5f; }
        *reinterpret_cast<f32x4*>(&xsh[xrow_off][xcol])        = a;
        *reinterpret_cast<f32x4*>(&xsh[xrow_off][xcol + 1024]) = b;
    }
    barrier_keep_vm();   // sl + xsh visible to all waves

    for (int i = 0; i < ITERS; ++i) {
        const int b = b0 + 2 * i + slot;

        // ---- prefetch iter i+1: x first, then r (so the x vmcnt-wait at the
        //      LDS write leaves the r loads in flight) ----
        if (i + 1 < ITERS) {
            const float* xp = xin + (size_t)(b0 + 2 * (i + 1) + xrow_off) * FEAT;
            nxa = *reinterpret_cast<const f32x4*>(xp + xcol);
            nxb = *reinterpret_cast<const f32x4*>(xp + xcol + 1024);
        }
        f32x2 n0, n1, n2;
        if (i + 1 < ITERS) {
            const f32x2* rg = reinterpret_cast<const f32x2*>(
                rr + ((size_t)(b + 2) * FEAT + fc) * 6);
            n0 = rg[lane]; n1 = rg[64 + lane]; n2 = rg[128 + lane];
        }

        // ---- ballot transpose (r9-verified) + LDS lut gather ----
        const float* xw = xsh[slot];
        const unsigned long long B0 = __ballot(xw[cc0[0]] >= r0[0]);
        const unsigned long long B1 = __ballot(xw[cc0[1]] >= r0[1]);
        const unsigned long long B2 = __ballot(xw[cc1[0]] >= r1[0]);
        const unsigned long long B3 = __ballot(xw[cc1[1]] >= r1[1]);
        const unsigned long long B4 = __ballot(xw[cc2[0]] >= r2[0]);
        const unsigned long long B5 = __ballot(xw[cc2[1]] >= r2[1]);

        int idx = 0;
        #pragma unroll
        for (int j = 0; j < 6; ++j) {
            const int e = 6 * lane + j;          // even => e&1 == j&1
            const int g = e >> 7;
            const unsigned long long src =
                (j & 1) ? ((g == 0) ? B1 : (g == 1) ? B3 : B5)
                        : ((g == 0) ? B0 : (g == 1) ? B2 : B4);
            idx |= (int)((src >> ((e & 127) >> 1)) & 1ull) << j;
        }

        const float v = sl[(ch * 64 + lane) * LUTSZ + idx];
        yout[(size_t)b * FEAT + fc + lane] = v;

        r0 = n0; r1 = n1; r2 = n2;

        // ---- rotate the shared x buffer ----
        barrier_keep_vm();                // all waves done gathering iter i
        if (i + 1 < ITERS) {
            f32x4 a = nxa, bb = nxb;      // vmcnt-waits x only (r after x)
            if (L == 0) { a = (a + 1.0f) * 0.5f; bb = (bb + 1.0f) * 0.5f; }
            *reinterpret_cast<f32x4*>(&xsh[xrow_off][xcol])        = a;
            *reinterpret_cast<f32x4*>(&xsh[xrow_off][xcol + 1024]) = bb;
            barrier_keep_vm();            // new rows visible
        }
    }
}

extern "C" void kernel_launch(void* const* d_in, const int* in_sizes, int n_in,
                              void* d_out, int out_size, void* d_ws, size_t ws_size,
                              hipStream_t stream) {
    const float* inputs = (const float*)d_in[0];
    const float* r1     = (const float*)d_in[1];
    const float* r2     = (const float*)d_in[2];
    const float* r3     = (const float*)d_in[3];
    const float* lut1   = (const float*)d_in[4];
    const float* lut2   = (const float*)d_in[5];
    const float* lut3   = (const float*)d_in[6];
    const int*   c1     = (const int*)d_in[7];
    const int*   c2     = (const int*)d_in[8];
    const int*   c3     = (const int*)d_in[9];
    float* out = (float*)d_out;

    const size_t n    = (size_t)BATCH * FEAT;
    const size_t lutn = (size_t)FEAT * LUTSZ;

    // ws layout: slut1 | slut2 | ws2   (17.8 MB total -- always fits)
    float* slut1 = (float*)d_ws;
    float* slut2 = slut1 + lutn;
    float* ws2   = slut2 + lutn;
    float* ws1   = out;                 // d_out doubles as L1 intermediate

    dim3 grid((FEAT / TF) * GROUPS), block(512);   // flat 512 blocks, swizzled

    sigmoid_lut_kernel<<<dim3(2 * lutn / 256), dim3(256), 0, stream>>>(
        lut1, lut2, slut1, slut2);

    lut_tile2<0><<<grid, block, 0, stream>>>(inputs, r1, c1, slut1, ws1);
    lut_tile2<1><<<grid, block, 0, stream>>>(ws1,    r2, c2, slut2, ws2);
    lut_tile2<1><<<grid, block, 0, stream>>>(ws2,    r3, c3, lut3,  out);
}

// Round 18
// 99.596 us; speedup vs baseline: 1.3568x; 1.0234x over previous
//
#include <hip/hip_runtime.h>
#include <math.h>

#define BATCH  2048
#define FEAT   2048
#define LUTSZ  64
#define TF     256
#define GROUPS 64
#define RPB    32            // rows per block
#define ITERS  (RPB / 2)     // 2 rows per iteration

typedef float f32x2 __attribute__((ext_vector_type(2)));
typedef int   i32x2 __attribute__((ext_vector_type(2)));
typedef float f32x4 __attribute__((ext_vector_type(4)));

// ---------------------------------------------------------------------------
// Round-18 = round-17 (101.9us) + two latency levers:
//  * s_setprio(1) around the post-barrier critical section (ballot gathers ->
//    extract -> lut gather -> store). The 2 resident blocks/CU sit at
//    different phases (gather vs staging) -> role diversity -> T5 applies
//    (attn precedent +4-7%; null only in lockstep structures).
//  * depth-2 x prefetch: x(i+2) issued at iter i, so the ds_write after
//    barrier A consumes 2-phase-old loads -> vmcnt wait provably ~0.
//
// Carried (all proven): TF=256 tile + 2-slot block-shared x (r14), XCD
// group-pin swizzle fid=tile*64+grp (r16, -17%), ballot transpose (r9),
// lgkmcnt-only barriers keeping vmem in flight (r14), unconditional slut
// precompute with d_out as L1 intermediate (r17), exact f32 chain:
// (v+1.0f)*0.5f ; sigmoid = 1.0f/(1.0f + RN32(exp_f64(-v))).
// ---------------------------------------------------------------------------

__device__ __forceinline__ void barrier_keep_vm() {
    __builtin_amdgcn_sched_barrier(0);
    asm volatile("s_waitcnt lgkmcnt(0)\n\ts_barrier" ::: "memory");
    __builtin_amdgcn_sched_barrier(0);
}

__global__ __launch_bounds__(256) void sigmoid_lut_kernel(
    const float* __restrict__ lut1, const float* __restrict__ lut2,
    float* __restrict__ slut1, float* __restrict__ slut2)
{
    const int n = FEAT * LUTSZ;
    int i = blockIdx.x * 256 + threadIdx.x;
    if (i < n) {
        float v = lut1[i];
        float e = (float)exp(-(double)v);     // correctly-rounded f32 exp
        slut1[i] = 1.0f / (1.0f + e);         // f32 IEEE chain (matches np)
    } else {
        i -= n;
        float v = lut2[i];
        float e = (float)exp(-(double)v);
        slut2[i] = 1.0f / (1.0f + e);
    }
}

// L: 0 = transform-in, 1 = plain input (lutg is slut or raw lut3)
template<int L>
__global__ __launch_bounds__(512, 4) void lut_tile2(
    const float* __restrict__ xin, const float* __restrict__ rr,
    const int* __restrict__ connect, const float* __restrict__ lutg,
    float* __restrict__ yout)
{
    __shared__ float sl[TF * LUTSZ];   // 64 KiB
    __shared__ float xsh[2][FEAT];     // 16 KiB  (2 row slots)

    // XCD swizzle: fid = tile*GROUPS + grp -> the 8 tile-blocks of a group
    // share fid mod 8 -> same XCD -> shared x rows are local-L2 hits.
    const int fid  = blockIdx.x;
    const int tile = fid >> 6;          // 0..7
    const int grp  = fid & 63;          // 0..63
    const int f0   = tile * TF;
    const int tid  = threadIdx.x, lane = tid & 63, w = tid >> 6;
    const int slot = w >> 2;           // 0/1: which row this wave computes
    const int ch   = w & 3;            // which 64-feature chunk
    const int fc   = f0 + ch * 64;

    // ---- stage lut tile (already sigmoid'd for layers 1-2) ----
    for (int i = tid; i < TF * LUTSZ; i += 512)
        sl[i] = lutg[(size_t)f0 * LUTSZ + i];

    // ---- connect regs for this wave's chunk (scrambled ballot layout) ----
    i32x2 cc0, cc1, cc2;
    {
        const i32x2* cg = reinterpret_cast<const i32x2*>(
            connect + (size_t)fc * 6);
        cc0 = cg[lane]; cc1 = cg[64 + lane]; cc2 = cg[128 + lane];
    }

    const int b0 = grp * RPB;

    // x staging map: thread covers 4 floats at xcol and 4 at xcol+1024 of
    // row (b0 + 2i + xrow_off)  -> conflict-free b128 LDS writes.
    const int xrow_off = tid >> 8;          // 0/1
    const int xcol     = (tid & 255) * 4;   // float offset

    // ---- prologue: stage x(iter0); issue x(iter1) [depth-2]; r(iter0) ----
    f32x4 pxa, pxb;    // x for the NEXT write (arrived / in flight)
    {
        const float* xp = xin + (size_t)(b0 + xrow_off) * FEAT;
        f32x4 a = *reinterpret_cast<const f32x4*>(xp + xcol);
        f32x4 b = *reinterpret_cast<const f32x4*>(xp + xcol + 1024);
        if (L == 0) { a = (a + 1.0f) * 0.5f; b = (b + 1.0f) * 0.5f; }
        *reinterpret_cast<f32x4*>(&xsh[xrow_off][xcol])        = a;
        *reinterpret_cast<f32x4*>(&xsh[xrow_off][xcol + 1024]) = b;
    }
    {
        const float* xp = xin + (size_t)(b0 + 2 + xrow_off) * FEAT;
        pxa = *reinterpret_cast<const f32x4*>(xp + xcol);
        pxb = *reinterpret_cast<const f32x4*>(xp + xcol + 1024);
    }
    f32x2 r0, r1, r2;
    {
        const f32x2* rg = reinterpret_cast<const f32x2*>(
            rr + ((size_t)(b0 + slot) * FEAT + fc) * 6);
        r0 = rg[lane]; r1 = rg[64 + lane]; r2 = rg[128 + lane];
    }
    barrier_keep_vm();   // sl + xsh visible to all waves

    for (int i = 0; i < ITERS; ++i) {
        const int b = b0 + 2 * i + slot;

        // ---- issue x(i+2) [depth-2] and r(i+1) prefetches ----
        f32x4 qxa, qxb;
        if (i + 2 < ITERS) {
            const float* xp = xin + (size_t)(b0 + 2 * (i + 2) + xrow_off) * FEAT;
            qxa = *reinterpret_cast<const f32x4*>(xp + xcol);
            qxb = *reinterpret_cast<const f32x4*>(xp + xcol + 1024);
        }
        f32x2 n0, n1, n2;
        if (i + 1 < ITERS) {
            const f32x2* rg = reinterpret_cast<const f32x2*>(
                rr + ((size_t)(b + 2) * FEAT + fc) * 6);
            n0 = rg[lane]; n1 = rg[64 + lane]; n2 = rg[128 + lane];
        }

        // ---- critical section: ballot transpose + LDS lut gather ----
        __builtin_amdgcn_s_setprio(1);
        const float* xw = xsh[slot];
        const unsigned long long B0 = __ballot(xw[cc0[0]] >= r0[0]);
        const unsigned long long B1 = __ballot(xw[cc0[1]] >= r0[1]);
        const unsigned long long B2 = __ballot(xw[cc1[0]] >= r1[0]);
        const unsigned long long B3 = __ballot(xw[cc1[1]] >= r1[1]);
        const unsigned long long B4 = __ballot(xw[cc2[0]] >= r2[0]);
        const unsigned long long B5 = __ballot(xw[cc2[1]] >= r2[1]);

        int idx = 0;
        #pragma unroll
        for (int j = 0; j < 6; ++j) {
            const int e = 6 * lane + j;          // even => e&1 == j&1
            const int g = e >> 7;
            const unsigned long long src =
                (j & 1) ? ((g == 0) ? B1 : (g == 1) ? B3 : B5)
                        : ((g == 0) ? B0 : (g == 1) ? B2 : B4);
            idx |= (int)((src >> ((e & 127) >> 1)) & 1ull) << j;
        }

        const float v = sl[(ch * 64 + lane) * LUTSZ + idx];
        yout[(size_t)b * FEAT + fc + lane] = v;
        __builtin_amdgcn_s_setprio(0);

        r0 = n0; r1 = n1; r2 = n2;

        // ---- rotate the shared x buffer (write 2-phase-old loads) ----
        barrier_keep_vm();                // all waves done gathering iter i
        if (i + 1 < ITERS) {
            f32x4 a = pxa, bb = pxb;      // issued at iter i-1: vmcnt wait ~0
            if (L == 0) { a = (a + 1.0f) * 0.5f; bb = (bb + 1.0f) * 0.5f; }
            *reinterpret_cast<f32x4*>(&xsh[xrow_off][xcol])        = a;
            *reinterpret_cast<f32x4*>(&xsh[xrow_off][xcol + 1024]) = bb;
            barrier_keep_vm();            // new rows visible
        }
        pxa = qxa; pxb = qxb;
    }
}

extern "C" void kernel_launch(void* const* d_in, const int* in_sizes, int n_in,
                              void* d_out, int out_size, void* d_ws, size_t ws_size,
                              hipStream_t stream) {
    const float* inputs = (const float*)d_in[0];
    const float* r1     = (const float*)d_in[1];
    const float* r2     = (const float*)d_in[2];
    const float* r3     = (const float*)d_in[3];
    const float* lut1   = (const float*)d_in[4];
    const float* lut2   = (const float*)d_in[5];
    const float* lut3   = (const float*)d_in[6];
    const int*   c1     = (const int*)d_in[7];
    const int*   c2     = (const int*)d_in[8];
    const int*   c3     = (const int*)d_in[9];
    float* out = (float*)d_out;

    const size_t n    = (size_t)BATCH * FEAT;
    const size_t lutn = (size_t)FEAT * LUTSZ;

    // ws layout: slut1 | slut2 | ws2   (17.8 MB total -- always fits)
    float* slut1 = (float*)d_ws;
    float* slut2 = slut1 + lutn;
    float* ws2   = slut2 + lutn;
    float* ws1   = out;                 // d_out doubles as L1 intermediate

    dim3 grid((FEAT / TF) * GROUPS), block(512);   // flat 512 blocks, swizzled

    sigmoid_lut_kernel<<<dim3(2 * lutn / 256), dim3(256), 0, stream>>>(
        lut1, lut2, slut1, slut2);

    lut_tile2<0><<<grid, block, 0, stream>>>(inputs, r1, c1, slut1, ws1);
    lut_tile2<1><<<grid, block, 0, stream>>>(ws1,    r2, c2, slut2, ws2);
    lut_tile2<1><<<grid, block, 0, stream>>>(ws2,    r3, c3, lut3,  out);
}